// Round 3
// baseline (544.069 us; speedup 1.0000x reference)
//
#include <hip/hip_runtime.h>
#include <math.h>

#define ETA 0.5f
#define KAPPA 0.1f
#define NUM_SAMPLES 100
#define DIM 1024
#define BATCH 1024
#define SPLIT 4                      // blocks per row for the pert scan
#define TPB 256
#define QF4 (NUM_SAMPLES * DIM / 4 / SPLIT)   // 6400 float4 per quarter-row

// Kernel 1: 4096 blocks; block (b,s) reduces sum-of-squares of quarter-row s
// of row b's perturbations [100,1024] f32. Partial -> ws[blockIdx.x].
__global__ __launch_bounds__(TPB) void psum_kernel(
    const float* __restrict__ pert, float* __restrict__ partial)
{
    const int blk = blockIdx.x;
    const int b   = blk >> 2;
    const int s   = blk & 3;
    const int tid = threadIdx.x;

    const float4* p4 = (const float4*)(pert + (size_t)b * NUM_SAMPLES * DIM) + s * QF4;

    float a0 = 0.f, a1 = 0.f;
    int k = 0;
    #pragma unroll 5
    for (int i = tid; i < QF4; i += TPB, ++k) {   // 25 iters/thread
        float4 v = p4[i];
        float t = v.x * v.x + v.y * v.y + v.z * v.z + v.w * v.w;
        if (k & 1) a1 += t; else a0 += t;
    }
    float psum = a0 + a1;

    #pragma unroll
    for (int off = 32; off > 0; off >>= 1)
        psum += __shfl_down(psum, off, 64);

    __shared__ float sp[TPB / 64];
    const int wave = tid >> 6;
    if ((tid & 63) == 0) sp[wave] = psum;
    __syncthreads();
    if (tid == 0) {
        float P = 0.f;
        #pragma unroll
        for (int w = 0; w < TPB / 64; ++w) P += sp[w];
        partial[blk] = P;   // every slot written -> no init needed under poison
    }
}

// Kernel 2: one block per row. Row norms of residue/cmani + combine partials
// + epilogue. Reads 8 KB/block.
__global__ __launch_bounds__(TPB) void finalize_kernel(
    const float* __restrict__ residue,
    const float* __restrict__ cmani,
    const float* __restrict__ partial,
    float* __restrict__ out)
{
    const int b   = blockIdx.x;
    const int tid = threadIdx.x;

    const float4* r4 = (const float4*)(residue + (size_t)b * DIM);
    float4 rv = r4[tid];
    float esum = rv.x * rv.x + rv.y * rv.y + rv.z * rv.z + rv.w * rv.w;

    const float4* c4 = (const float4*)(cmani + (size_t)b * DIM);
    float4 cv = c4[tid];
    float csum = cv.x * cv.x + cv.y * cv.y + cv.z * cv.z + cv.w * cv.w;

    #pragma unroll
    for (int off = 32; off > 0; off >>= 1) {
        esum += __shfl_down(esum, off, 64);
        csum += __shfl_down(csum, off, 64);
    }
    __shared__ float se[TPB / 64], sc[TPB / 64];
    const int wave = tid >> 6;
    if ((tid & 63) == 0) { se[wave] = esum; sc[wave] = csum; }
    __syncthreads();

    if (tid == 0) {
        float E = 0.f, C = 0.f;
        #pragma unroll
        for (int w = 0; w < TPB / 64; ++w) { E += se[w]; C += sc[w]; }
        float P = partial[b * SPLIT + 0] + partial[b * SPLIT + 1]
                + partial[b * SPLIT + 2] + partial[b * SPLIT + 3];

        float dispersion     = P / (float)NUM_SAMPLES;
        float scale          = sqrtf(C);
        float energy_density = E / (scale + 1e-8f);
        float localization   = (E > 0.f) ? (ETA / (energy_density + 1e-8f)) : scale;
        float ratio          = dispersion / (localization + 1e-8f);

        out[0 * BATCH + b] = (ratio < KAPPA) ? 1.0f : 0.0f;
        out[1 * BATCH + b] = dispersion;
        out[2 * BATCH + b] = localization;
        out[3 * BATCH + b] = ratio;
    }
}

extern "C" void kernel_launch(void* const* d_in, const int* in_sizes, int n_in,
                              void* d_out, int out_size, void* d_ws, size_t ws_size,
                              hipStream_t stream) {
    const float* residue = (const float*)d_in[0];
    const float* cmani   = (const float*)d_in[1];
    const float* pert    = (const float*)d_in[2];
    float* out     = (float*)d_out;
    float* partial = (float*)d_ws;   // BATCH*SPLIT floats = 16 KB

    psum_kernel<<<BATCH * SPLIT, TPB, 0, stream>>>(pert, partial);
    finalize_kernel<<<BATCH, TPB, 0, stream>>>(residue, cmani, partial, out);
}